// Round 5
// baseline (728.397 us; speedup 1.0000x reference)
//
#include <hip/hip_runtime.h>
#include <stdint.h>

// Problem constants
#define Bz  4
#define Sz  2048
#define Hz  1024
#define NHz 8
#define HDz 128
#define Mz  (Bz*Sz)          // 8192 rows for all GEMMs

typedef __attribute__((ext_vector_type(8))) short bf16x8;   // 8 bf16 = 4 VGPRs
typedef __attribute__((ext_vector_type(4))) float f32x4;

__device__ __forceinline__ unsigned short f2bf(float x) {
  union { float f; unsigned int u; } c; c.f = x;
  unsigned int u = c.u;
  return (unsigned short)((u + 0x7FFFu + ((u >> 16) & 1u)) >> 16);  // RNE
}

__device__ __forceinline__ void gl2lds16(const unsigned short* g, unsigned short* l) {
  __builtin_amdgcn_global_load_lds(
      (const __attribute__((address_space(1))) unsigned int*)g,
      (__attribute__((address_space(3))) unsigned int*)l, 16, 0, 0);
}

// ---------------------------------------------------------------- cvt f32->bf16
__global__ __launch_bounds__(256)
void cvt_kernel(const float* __restrict__ in, unsigned short* __restrict__ out, int n) {
  const int n4 = n >> 2;
  for (int i = blockIdx.x * blockDim.x + threadIdx.x; i < n4; i += gridDim.x * blockDim.x) {
    float4 v = ((const float4*)in)[i];
    ushort4 o;
    o.x = f2bf(v.x); o.y = f2bf(v.y); o.z = f2bf(v.z); o.w = f2bf(v.w);
    ((ushort4*)out)[i] = o;
  }
}

__global__ __launch_bounds__(256)
void cvt4_kernel(const float* __restrict__ w0, const float* __restrict__ w1,
                 const float* __restrict__ w2, const float* __restrict__ w3,
                 unsigned short* __restrict__ o0, unsigned short* __restrict__ o1,
                 unsigned short* __restrict__ o2, unsigned short* __restrict__ o3) {
  const int which = blockIdx.y;
  const float* in = (which == 0) ? w0 : (which == 1) ? w1 : (which == 2) ? w2 : w3;
  unsigned short* out = (which == 0) ? o0 : (which == 1) ? o1 : (which == 2) ? o2 : o3;
  const int n4 = (Hz * Hz) >> 2;
  for (int i = blockIdx.x * blockDim.x + threadIdx.x; i < n4; i += gridDim.x * blockDim.x) {
    float4 v = ((const float4*)in)[i];
    ushort4 o;
    o.x = f2bf(v.x); o.y = f2bf(v.y); o.z = f2bf(v.z); o.w = f2bf(v.w);
    ((ushort4*)out)[i] = o;
  }
}

// ---------------------------------------------------------------- GEMM cores
// C = A * Bw^T, 128x128 tile, BK=64, 4 waves. Shared by fused-QKV and Wo kernels.
#define GEMM_PROLOG()                                                           \
  __shared__ __align__(16) unsigned short Asm[128 * 64];                        \
  __shared__ __align__(16) unsigned short Bsm[128 * 64];                        \
  const int tid = threadIdx.x;                                                  \
  const int w  = tid >> 6, l = tid & 63;                                        \
  const int lc = l & 15,  lg = l >> 4;                                          \
  const int wr = w >> 1,  wc = w & 1;                                           \
  const int bm = blockIdx.x * 128;                                              \
  const int bn = blockIdx.y * 128;                                              \
  f32x4 acc[4][4];                                                              \
  _Pragma("unroll")                                                             \
  for (int i = 0; i < 4; i++)                                                   \
    _Pragma("unroll")                                                           \
    for (int j = 0; j < 4; j++) acc[i][j] = (f32x4){0.f, 0.f, 0.f, 0.f};        \
  const int srow = w * 32 + (l >> 3);                                           \
  const int scol = (l & 7) * 8;                                                 \
  for (int kt = 0; kt < 16; kt++) {                                             \
    const int k0 = kt * 64;                                                     \
    __syncthreads();                                                            \
    _Pragma("unroll")                                                           \
    for (int i = 0; i < 4; i++) {                                               \
      gl2lds16(A  + (size_t)(bm + srow + i * 8) * Hz + k0 + scol,               \
               &Asm[(w * 32 + i * 8) * 64]);                                    \
      gl2lds16(Bw + (size_t)(bn + srow + i * 8) * Hz + k0 + scol,               \
               &Bsm[(w * 32 + i * 8) * 64]);                                    \
    }                                                                           \
    __syncthreads();                                                            \
    _Pragma("unroll")                                                           \
    for (int kk = 0; kk < 2; kk++) {                                            \
      bf16x8 af[4], bf[4];                                                      \
      _Pragma("unroll")                                                         \
      for (int t = 0; t < 4; t++) {                                             \
        af[t] = *(const bf16x8*)&Asm[(wr*64 + t*16 + lc)*64 + kk*32 + lg*8];    \
        bf[t] = *(const bf16x8*)&Bsm[(wc*64 + t*16 + lc)*64 + kk*32 + lg*8];    \
      }                                                                         \
      _Pragma("unroll")                                                         \
      for (int mt = 0; mt < 4; mt++)                                            \
        _Pragma("unroll")                                                       \
        for (int nt = 0; nt < 4; nt++)                                          \
          acc[mt][nt] = __builtin_amdgcn_mfma_f32_16x16x32_bf16(                \
              af[mt], bf[nt], acc[mt][nt], 0, 0, 0);                            \
    }                                                                           \
  }

// fused Q/K/V projection: blockIdx.z selects weight & destination
__global__ __launch_bounds__(256)
void gemm_qkv(const unsigned short* __restrict__ A,
              const unsigned short* __restrict__ W0,
              const unsigned short* __restrict__ W1,
              const unsigned short* __restrict__ W2,
              unsigned short* __restrict__ Qo,
              unsigned short* __restrict__ Ko,
              unsigned short* __restrict__ Vto, float qscale)
{
  const int z = blockIdx.z;
  const unsigned short* Bw = (z == 0) ? W0 : (z == 1) ? W1 : W2;
  const float alpha = (z == 0) ? qscale : 1.0f;
  GEMM_PROLOG()

#pragma unroll
  for (int mt = 0; mt < 4; mt++) {
#pragma unroll
    for (int nt = 0; nt < 4; nt++) {
      const int row0 = bm + wr * 64 + mt * 16 + lg * 4;
      const int col  = bn + wc * 64 + nt * 16 + lc;
      if (z == 2) {
        // V^T layout: [(b*NH+nh)*HD + hd][S]
        ushort4 pk;
        pk.x = f2bf(acc[mt][nt][0]);
        pk.y = f2bf(acc[mt][nt][1]);
        pk.z = f2bf(acc[mt][nt][2]);
        pk.w = f2bf(acc[mt][nt][3]);
        const size_t idx = ((size_t)((row0 >> 11) << 10) + col) * Sz + (row0 & 2047);
        *(ushort4*)&Vto[idx] = pk;
      } else {
        unsigned short* C = (z == 0) ? Qo : Ko;
#pragma unroll
        for (int r = 0; r < 4; r++)
          C[(size_t)(row0 + r) * Hz + col] = f2bf(acc[mt][nt][r] * alpha);
      }
    }
  }
}

// output projection: f32 out
__global__ __launch_bounds__(256)
void gemm_out(const unsigned short* __restrict__ A,
              const unsigned short* __restrict__ Bw,
              float* __restrict__ C)
{
  GEMM_PROLOG()
#pragma unroll
  for (int mt = 0; mt < 4; mt++)
#pragma unroll
    for (int nt = 0; nt < 4; nt++) {
      const int row0 = bm + wr * 64 + mt * 16 + lg * 4;
      const int col  = bn + wc * 64 + nt * 16 + lc;
#pragma unroll
      for (int r = 0; r < 4; r++)
        C[(size_t)(row0 + r) * Hz + col] = acc[mt][nt][r];
    }
}

// ---------------------------------------------------------------- flash attention
// Q,K: [B,S,H] bf16 (Q pre-scaled by log2(e)/sqrt(128));  Vt: [B*NH*HD][S] bf16
// 4 waves, 128 q/block. K dbuf in LDS (single barrier/iter); V direct from L2;
// P via per-wave LDS. 40KB LDS -> 4 blocks/CU.
__global__ __launch_bounds__(256, 4)
void attn_fwd(const unsigned short* __restrict__ Q,
              const unsigned short* __restrict__ K,
              const unsigned short* __restrict__ Vt,
              unsigned short* __restrict__ O)
{
  // bijective XCD swizzle: 512 blocks, 64 consecutive wg per XCD (4 heads/XCD)
  const int bid = blockIdx.x;
  const int wg  = (bid & 7) * 64 + (bid >> 3);
  const int qb  = wg & 15;
  const int bh  = wg >> 4;
  const int b = bh >> 3, nh = bh & 7;
  const int w = threadIdx.x >> 6, l = threadIdx.x & 63;
  const int lc = l & 15, lg = l >> 4;

  __shared__ __align__(16) unsigned short Ksm[2][64 * 128]; // 32 KB dbuf
  __shared__ __align__(16) unsigned short Psm[4][16 * 64];  //  8 KB per-wave

  bf16x8 qf[2][4];
#pragma unroll
  for (int mt = 0; mt < 2; mt++)
#pragma unroll
    for (int ks = 0; ks < 4; ks++)
      qf[mt][ks] = *(const bf16x8*)(Q + ((size_t)b * Sz + qb * 128 + w * 32 + mt * 16 + lc) * Hz
                                      + nh * HDz + ks * 32 + lg * 8);

  const unsigned short* Kbase = K  + (size_t)b * Sz * Hz + nh * HDz;
  const unsigned short* Vbase = Vt + (size_t)bh * HDz * Sz;

  f32x4 acc[2][8];
#pragma unroll
  for (int mt = 0; mt < 2; mt++)
#pragma unroll
    for (int i = 0; i < 8; i++) acc[mt][i] = (f32x4){0.f, 0.f, 0.f, 0.f};
  float mrow[2][4], lrow[2][4];
#pragma unroll
  for (int mt = 0; mt < 2; mt++)
#pragma unroll
    for (int r = 0; r < 4; r++) { mrow[mt][r] = -1e30f; lrow[mt][r] = 0.f; }

  // K tile [64 s][128 d]: linear LDS dest + involution-swizzled global source
  #define STAGE_K(BUF, KT) {                                                          \
    _Pragma("unroll")                                                                 \
    for (int i = 0; i < 4; i++) {                                                     \
      const int r = w * 16 + i * 4 + (l >> 4);                                        \
      gl2lds16(Kbase + (size_t)((KT) * 64 + r) * Hz + (((l & 15) ^ (r & 7)) * 8),     \
               &Ksm[BUF][(w * 16 + i * 4) * 128]);                                    \
    } }

  int cur = 0;
  STAGE_K(0, 0);
  __syncthreads();

  for (int kt = 0; kt < Sz / 64; kt++) {
    if (kt < Sz / 64 - 1) STAGE_K(cur ^ 1, kt + 1);   // async prefetch next K

    // ---- QK^T from Ksm[cur]
    f32x4 s[2][4];
#pragma unroll
    for (int mt = 0; mt < 2; mt++)
#pragma unroll
      for (int nt = 0; nt < 4; nt++) s[mt][nt] = (f32x4){0.f, 0.f, 0.f, 0.f};
    __builtin_amdgcn_s_setprio(1);
#pragma unroll
    for (int ks = 0; ks < 4; ks++) {
#pragma unroll
      for (int nt = 0; nt < 4; nt++) {
        bf16x8 kf = *(const bf16x8*)&Ksm[cur][(nt * 16 + lc) * 128 + (((ks * 4 + lg) ^ (lc & 7)) * 8)];
#pragma unroll
        for (int mt = 0; mt < 2; mt++)
          s[mt][nt] = __builtin_amdgcn_mfma_f32_16x16x32_bf16(qf[mt][ks], kf, s[mt][nt], 0, 0, 0);
      }
    }
    __builtin_amdgcn_s_setprio(0);

    // ---- online softmax (exp2-space, defer-max THR=8)
#pragma unroll
    for (int mt = 0; mt < 2; mt++) {
#pragma unroll
      for (int r = 0; r < 4; r++) {
        float tm = fmaxf(fmaxf(s[mt][0][r], s[mt][1][r]), fmaxf(s[mt][2][r], s[mt][3][r]));
        tm = fmaxf(tm, __shfl_xor(tm, 1));
        tm = fmaxf(tm, __shfl_xor(tm, 2));
        tm = fmaxf(tm, __shfl_xor(tm, 4));
        tm = fmaxf(tm, __shfl_xor(tm, 8));
        if (tm > mrow[mt][r] + 8.0f) {
          const float sc = exp2f(mrow[mt][r] - tm);
          mrow[mt][r] = tm;
          lrow[mt][r] *= sc;
#pragma unroll
          for (int nt = 0; nt < 8; nt++) acc[mt][nt][r] *= sc;
        }
        float rs = 0.f;
#pragma unroll
        for (int nt = 0; nt < 4; nt++) {
          float p = exp2f(s[mt][nt][r] - mrow[mt][r]);
          s[mt][nt][r] = p;
          rs += p;
        }
        rs += __shfl_xor(rs, 1);
        rs += __shfl_xor(rs, 2);
        rs += __shfl_xor(rs, 4);
        rs += __shfl_xor(rs, 8);
        lrow[mt][r] += rs;
      }
    }

    // ---- P -> per-wave LDS (swizzled) -> A-fragments
    bf16x8 pf[2][2];
#pragma unroll
    for (int mt = 0; mt < 2; mt++) {
#pragma unroll
      for (int nt = 0; nt < 4; nt++)
#pragma unroll
        for (int r = 0; r < 4; r++) {
          const int row = lg * 4 + r;
          const int ch  = (nt * 2 + (lc >> 3)) ^ (row & 7);
          Psm[w][row * 64 + ch * 8 + (lc & 7)] = f2bf(s[mt][nt][r]);
        }
#pragma unroll
      for (int kk = 0; kk < 2; kk++)
        pf[mt][kk] = *(const bf16x8*)&Psm[w][lc * 64 + (((kk * 4 + lg) ^ (lc & 7)) * 8)];
    }

    // ---- PV: V B-fragments straight from global (L2-resident per XCD)
    __builtin_amdgcn_s_setprio(1);
#pragma unroll
    for (int kk = 0; kk < 2; kk++) {
#pragma unroll
      for (int nt = 0; nt < 8; nt++) {
        bf16x8 vf = *(const bf16x8*)(Vbase + (size_t)(nt * 16 + lc) * Sz + kt * 64 + kk * 32 + lg * 8);
        acc[0][nt] = __builtin_amdgcn_mfma_f32_16x16x32_bf16(pf[0][kk], vf, acc[0][nt], 0, 0, 0);
        acc[1][nt] = __builtin_amdgcn_mfma_f32_16x16x32_bf16(pf[1][kk], vf, acc[1][nt], 0, 0, 0);
      }
    }
    __builtin_amdgcn_s_setprio(0);

    __syncthreads();   // K[t+1] resident; all waves done with Ksm[cur] & Psm
    cur ^= 1;
  }

  // ---- epilogue (hoisted reciprocal)
#pragma unroll
  for (int mt = 0; mt < 2; mt++) {
    float inv[4];
#pragma unroll
    for (int r = 0; r < 4; r++) inv[r] = 1.0f / lrow[mt][r];
#pragma unroll
    for (int nt = 0; nt < 8; nt++)
#pragma unroll
      for (int r = 0; r < 4; r++) {
        const size_t row = (size_t)b * Sz + qb * 128 + w * 32 + mt * 16 + lg * 4 + r;
        O[row * Hz + nh * HDz + nt * 16 + lc] = f2bf(acc[mt][nt][r] * inv[r]);
      }
  }
}

// ---------------------------------------------------------------- launch
extern "C" void kernel_launch(void* const* d_in, const int* in_sizes, int n_in,
                              void* d_out, int out_size, void* d_ws, size_t ws_size,
                              hipStream_t stream) {
  const float* hs = (const float*)d_in[0];
  const float* Wq = (const float*)d_in[1];
  const float* Wk = (const float*)d_in[2];
  const float* Wv = (const float*)d_in[3];
  const float* Wo = (const float*)d_in[4];

  const size_t NEL = (size_t)Mz * Hz;   // 8388608
  const size_t WEL = (size_t)Hz * Hz;   // 1048576

  unsigned short* p = (unsigned short*)d_ws;
  unsigned short* hs_bf = p; p += NEL;
  unsigned short* Wq_bf = p; p += WEL;
  unsigned short* Wk_bf = p; p += WEL;
  unsigned short* Wv_bf = p; p += WEL;
  unsigned short* Wo_bf = p; p += WEL;
  unsigned short* Qb    = p; p += NEL;
  unsigned short* Kb    = p; p += NEL;
  unsigned short* Vtb   = p; p += NEL;
  unsigned short* Ob    = hs_bf;        // alias: hs_bf dead after QKV GEMM

  cvt_kernel<<<2048, 256, 0, stream>>>(hs, hs_bf, (int)NEL);
  cvt4_kernel<<<dim3(512, 4), 256, 0, stream>>>(Wq, Wk, Wv, Wo,
                                                Wq_bf, Wk_bf, Wv_bf, Wo_bf);

  const float qscale = 0.08838834764831845f * 1.44269504088896340736f; // 1/sqrt(128)*log2(e)
  gemm_qkv<<<dim3(Mz / 128, Hz / 128, 3), 256, 0, stream>>>(
      hs_bf, Wq_bf, Wk_bf, Wv_bf, Qb, Kb, Vtb, qscale);

  attn_fwd<<<512, 256, 0, stream>>>(Qb, Kb, Vtb, Ob);

  gemm_out<<<dim3(Mz / 128, Hz / 128), 256, 0, stream>>>(Ob, Wo_bf, (float*)d_out);
}

// Round 6
// 542.513 us; speedup vs baseline: 1.3426x; 1.3426x over previous
//
#include <hip/hip_runtime.h>
#include <stdint.h>

// Problem constants
#define Bz  4
#define Sz  2048
#define Hz  1024
#define NHz 8
#define HDz 128
#define Mz  (Bz*Sz)          // 8192 rows for all GEMMs

typedef __attribute__((ext_vector_type(8))) short bf16x8;   // 8 bf16 = 4 VGPRs
typedef __attribute__((ext_vector_type(4))) float f32x4;

__device__ __forceinline__ unsigned short f2bf(float x) {
  union { float f; unsigned int u; } c; c.f = x;
  unsigned int u = c.u;
  return (unsigned short)((u + 0x7FFFu + ((u >> 16) & 1u)) >> 16);  // RNE
}

__device__ __forceinline__ void gl2lds16(const unsigned short* g, unsigned short* l) {
  __builtin_amdgcn_global_load_lds(
      (const __attribute__((address_space(1))) unsigned int*)g,
      (__attribute__((address_space(3))) unsigned int*)l, 16, 0, 0);
}

// ---------------------------------------------------------------- cvt f32->bf16
__global__ __launch_bounds__(256)
void cvt_kernel(const float* __restrict__ in, unsigned short* __restrict__ out, int n) {
  const int n4 = n >> 2;
  for (int i = blockIdx.x * blockDim.x + threadIdx.x; i < n4; i += gridDim.x * blockDim.x) {
    float4 v = ((const float4*)in)[i];
    ushort4 o;
    o.x = f2bf(v.x); o.y = f2bf(v.y); o.z = f2bf(v.z); o.w = f2bf(v.w);
    ((ushort4*)out)[i] = o;
  }
}

__global__ __launch_bounds__(256)
void cvt4_kernel(const float* __restrict__ w0, const float* __restrict__ w1,
                 const float* __restrict__ w2, const float* __restrict__ w3,
                 unsigned short* __restrict__ o0, unsigned short* __restrict__ o1,
                 unsigned short* __restrict__ o2, unsigned short* __restrict__ o3) {
  const int which = blockIdx.y;
  const float* in = (which == 0) ? w0 : (which == 1) ? w1 : (which == 2) ? w2 : w3;
  unsigned short* out = (which == 0) ? o0 : (which == 1) ? o1 : (which == 2) ? o2 : o3;
  const int n4 = (Hz * Hz) >> 2;
  for (int i = blockIdx.x * blockDim.x + threadIdx.x; i < n4; i += gridDim.x * blockDim.x) {
    float4 v = ((const float4*)in)[i];
    ushort4 o;
    o.x = f2bf(v.x); o.y = f2bf(v.y); o.z = f2bf(v.z); o.w = f2bf(v.w);
    ((ushort4*)out)[i] = o;
  }
}

// ---------------------------------------------------------------- GEMM cores
// C = A * Bw^T, 128x128 tile, BK=64, 4 waves. Shared by fused-QKV and Wo kernels.
#define GEMM_PROLOG()                                                           \
  __shared__ __align__(16) unsigned short Asm[128 * 64];                        \
  __shared__ __align__(16) unsigned short Bsm[128 * 64];                        \
  const int tid = threadIdx.x;                                                  \
  const int w  = tid >> 6, l = tid & 63;                                        \
  const int lc = l & 15,  lg = l >> 4;                                          \
  const int wr = w >> 1,  wc = w & 1;                                           \
  const int bm = blockIdx.x * 128;                                              \
  const int bn = blockIdx.y * 128;                                              \
  f32x4 acc[4][4];                                                              \
  _Pragma("unroll")                                                             \
  for (int i = 0; i < 4; i++)                                                   \
    _Pragma("unroll")                                                           \
    for (int j = 0; j < 4; j++) acc[i][j] = (f32x4){0.f, 0.f, 0.f, 0.f};        \
  const int srow = w * 32 + (l >> 3);                                           \
  const int scol = (l & 7) * 8;                                                 \
  for (int kt = 0; kt < 16; kt++) {                                             \
    const int k0 = kt * 64;                                                     \
    __syncthreads();                                                            \
    _Pragma("unroll")                                                           \
    for (int i = 0; i < 4; i++) {                                               \
      gl2lds16(A  + (size_t)(bm + srow + i * 8) * Hz + k0 + scol,               \
               &Asm[(w * 32 + i * 8) * 64]);                                    \
      gl2lds16(Bw + (size_t)(bn + srow + i * 8) * Hz + k0 + scol,               \
               &Bsm[(w * 32 + i * 8) * 64]);                                    \
    }                                                                           \
    __syncthreads();                                                            \
    _Pragma("unroll")                                                           \
    for (int kk = 0; kk < 2; kk++) {                                            \
      bf16x8 af[4], bf[4];                                                      \
      _Pragma("unroll")                                                         \
      for (int t = 0; t < 4; t++) {                                             \
        af[t] = *(const bf16x8*)&Asm[(wr*64 + t*16 + lc)*64 + kk*32 + lg*8];    \
        bf[t] = *(const bf16x8*)&Bsm[(wc*64 + t*16 + lc)*64 + kk*32 + lg*8];    \
      }                                                                         \
      _Pragma("unroll")                                                         \
      for (int mt = 0; mt < 4; mt++)                                            \
        _Pragma("unroll")                                                       \
        for (int nt = 0; nt < 4; nt++)                                          \
          acc[mt][nt] = __builtin_amdgcn_mfma_f32_16x16x32_bf16(                \
              af[mt], bf[nt], acc[mt][nt], 0, 0, 0);                            \
    }                                                                           \
  }

// fused Q/K/V projection: blockIdx.z selects weight & destination
__global__ __launch_bounds__(256)
void gemm_qkv(const unsigned short* __restrict__ A,
              const unsigned short* __restrict__ W0,
              const unsigned short* __restrict__ W1,
              const unsigned short* __restrict__ W2,
              unsigned short* __restrict__ Qo,
              unsigned short* __restrict__ Ko,
              unsigned short* __restrict__ Vto, float qscale)
{
  const int z = blockIdx.z;
  const unsigned short* Bw = (z == 0) ? W0 : (z == 1) ? W1 : W2;
  const float alpha = (z == 0) ? qscale : 1.0f;
  GEMM_PROLOG()

#pragma unroll
  for (int mt = 0; mt < 4; mt++) {
#pragma unroll
    for (int nt = 0; nt < 4; nt++) {
      const int row0 = bm + wr * 64 + mt * 16 + lg * 4;
      const int col  = bn + wc * 64 + nt * 16 + lc;
      if (z == 2) {
        // V^T layout: [(b*NH+nh)*HD + hd][S]
        ushort4 pk;
        pk.x = f2bf(acc[mt][nt][0]);
        pk.y = f2bf(acc[mt][nt][1]);
        pk.z = f2bf(acc[mt][nt][2]);
        pk.w = f2bf(acc[mt][nt][3]);
        const size_t idx = ((size_t)((row0 >> 11) << 10) + col) * Sz + (row0 & 2047);
        *(ushort4*)&Vto[idx] = pk;
      } else {
        unsigned short* C = (z == 0) ? Qo : Ko;
#pragma unroll
        for (int r = 0; r < 4; r++)
          C[(size_t)(row0 + r) * Hz + col] = f2bf(acc[mt][nt][r] * alpha);
      }
    }
  }
}

// output projection: f32 out
__global__ __launch_bounds__(256)
void gemm_out(const unsigned short* __restrict__ A,
              const unsigned short* __restrict__ Bw,
              float* __restrict__ C)
{
  GEMM_PROLOG()
#pragma unroll
  for (int mt = 0; mt < 4; mt++)
#pragma unroll
    for (int nt = 0; nt < 4; nt++) {
      const int row0 = bm + wr * 64 + mt * 16 + lg * 4;
      const int col  = bn + wc * 64 + nt * 16 + lc;
#pragma unroll
      for (int r = 0; r < 4; r++)
        C[(size_t)(row0 + r) * Hz + col] = acc[mt][nt][r];
    }
}

// ---------------------------------------------------------------- flash attention
// Q,K: [B,S,H] bf16 (Q pre-scaled by log2(e)/sqrt(128));  Vt: [B*NH*HD][S] bf16
// 4 waves x 16 q-rows = 64 q/block; grid 1024 = 4 blocks/CU (16 waves/CU).
// K dbuf in LDS (single barrier/iter); V direct from L2; P via per-wave LDS.
// LDS 40KB. No min-wave bound (round-5 spill lesson: footprint ~100 VGPR, let
// the compiler allocate naturally; 4 waves/SIMD fits if <=128).
__global__ __launch_bounds__(256)
void attn_fwd(const unsigned short* __restrict__ Q,
              const unsigned short* __restrict__ K,
              const unsigned short* __restrict__ Vt,
              unsigned short* __restrict__ O)
{
  // bijective XCD swizzle: 1024 blocks, 128 consecutive wg per XCD (4 heads/XCD)
  const int bid = blockIdx.x;
  const int wg  = (bid & 7) * 128 + (bid >> 3);
  const int qb  = wg & 31;               // q-block: rows qb*64..+63
  const int bh  = wg >> 5;               // 0..31
  const int b = bh >> 3, nh = bh & 7;
  const int w = threadIdx.x >> 6, l = threadIdx.x & 63;
  const int lc = l & 15, lg = l >> 4;

  __shared__ __align__(16) unsigned short Ksm[2][64 * 128]; // 32 KB dbuf
  __shared__ __align__(16) unsigned short Psm[4][16 * 64];  //  8 KB per-wave

  bf16x8 qf[4];
#pragma unroll
  for (int ks = 0; ks < 4; ks++)
    qf[ks] = *(const bf16x8*)(Q + ((size_t)b * Sz + qb * 64 + w * 16 + lc) * Hz
                                + nh * HDz + ks * 32 + lg * 8);

  const unsigned short* Kbase = K  + (size_t)b * Sz * Hz + nh * HDz;
  const unsigned short* Vbase = Vt + (size_t)bh * HDz * Sz;

  f32x4 acc[8];
#pragma unroll
  for (int i = 0; i < 8; i++) acc[i] = (f32x4){0.f, 0.f, 0.f, 0.f};
  float mrow[4], lrow[4];
#pragma unroll
  for (int r = 0; r < 4; r++) { mrow[r] = -1e30f; lrow[r] = 0.f; }

  // K tile [64 s][128 d]: linear LDS dest + involution-swizzled global source
  #define STAGE_K(BUF, KT) {                                                          \
    _Pragma("unroll")                                                                 \
    for (int i = 0; i < 4; i++) {                                                     \
      const int r = w * 16 + i * 4 + (l >> 4);                                        \
      gl2lds16(Kbase + (size_t)((KT) * 64 + r) * Hz + (((l & 15) ^ (r & 7)) * 8),     \
               &Ksm[BUF][(w * 16 + i * 4) * 128]);                                    \
    } }

  int cur = 0;
  STAGE_K(0, 0);
  __syncthreads();

  for (int kt = 0; kt < Sz / 64; kt++) {
    if (kt < Sz / 64 - 1) STAGE_K(cur ^ 1, kt + 1);   // async prefetch next K

    // ---- QK^T from Ksm[cur]
    f32x4 s[4];
#pragma unroll
    for (int nt = 0; nt < 4; nt++) s[nt] = (f32x4){0.f, 0.f, 0.f, 0.f};
    __builtin_amdgcn_s_setprio(1);
#pragma unroll
    for (int ks = 0; ks < 4; ks++) {
#pragma unroll
      for (int nt = 0; nt < 4; nt++) {
        bf16x8 kf = *(const bf16x8*)&Ksm[cur][(nt * 16 + lc) * 128 + (((ks * 4 + lg) ^ (lc & 7)) * 8)];
        s[nt] = __builtin_amdgcn_mfma_f32_16x16x32_bf16(qf[ks], kf, s[nt], 0, 0, 0);
      }
    }
    __builtin_amdgcn_s_setprio(0);

    // ---- online softmax (exp2-space, defer-max THR=8)
#pragma unroll
    for (int r = 0; r < 4; r++) {
      float tm = fmaxf(fmaxf(s[0][r], s[1][r]), fmaxf(s[2][r], s[3][r]));
      tm = fmaxf(tm, __shfl_xor(tm, 1));
      tm = fmaxf(tm, __shfl_xor(tm, 2));
      tm = fmaxf(tm, __shfl_xor(tm, 4));
      tm = fmaxf(tm, __shfl_xor(tm, 8));
      if (tm > mrow[r] + 8.0f) {
        const float sc = exp2f(mrow[r] - tm);
        mrow[r] = tm;
        lrow[r] *= sc;
#pragma unroll
        for (int nt = 0; nt < 8; nt++) acc[nt][r] *= sc;
      }
      float rs = 0.f;
#pragma unroll
      for (int nt = 0; nt < 4; nt++) {
        float p = exp2f(s[nt][r] - mrow[r]);
        s[nt][r] = p;
        rs += p;
      }
      rs += __shfl_xor(rs, 1);
      rs += __shfl_xor(rs, 2);
      rs += __shfl_xor(rs, 4);
      rs += __shfl_xor(rs, 8);
      lrow[r] += rs;
    }

    // ---- P -> per-wave LDS (swizzled) -> A-fragments
#pragma unroll
    for (int nt = 0; nt < 4; nt++)
#pragma unroll
      for (int r = 0; r < 4; r++) {
        const int row = lg * 4 + r;
        const int ch  = (nt * 2 + (lc >> 3)) ^ (row & 7);
        Psm[w][row * 64 + ch * 8 + (lc & 7)] = f2bf(s[nt][r]);
      }
    bf16x8 pf[2];
#pragma unroll
    for (int kk = 0; kk < 2; kk++)
      pf[kk] = *(const bf16x8*)&Psm[w][lc * 64 + (((kk * 4 + lg) ^ (lc & 7)) * 8)];

    // ---- PV: V B-fragments straight from global (L2-resident per XCD)
    __builtin_amdgcn_s_setprio(1);
#pragma unroll
    for (int kk = 0; kk < 2; kk++) {
#pragma unroll
      for (int nt = 0; nt < 8; nt++) {
        bf16x8 vf = *(const bf16x8*)(Vbase + (size_t)(nt * 16 + lc) * Sz + kt * 64 + kk * 32 + lg * 8);
        acc[nt] = __builtin_amdgcn_mfma_f32_16x16x32_bf16(pf[kk], vf, acc[nt], 0, 0, 0);
      }
    }
    __builtin_amdgcn_s_setprio(0);

    __syncthreads();   // K[t+1] resident; all waves done with Ksm[cur] & Psm
    cur ^= 1;
  }

  // ---- epilogue (hoisted reciprocal)
  float inv[4];
#pragma unroll
  for (int r = 0; r < 4; r++) inv[r] = 1.0f / lrow[r];
#pragma unroll
  for (int nt = 0; nt < 8; nt++)
#pragma unroll
    for (int r = 0; r < 4; r++) {
      const size_t row = (size_t)b * Sz + qb * 64 + w * 16 + lg * 4 + r;
      O[row * Hz + nh * HDz + nt * 16 + lc] = f2bf(acc[nt][r] * inv[r]);
    }
}

// ---------------------------------------------------------------- launch
extern "C" void kernel_launch(void* const* d_in, const int* in_sizes, int n_in,
                              void* d_out, int out_size, void* d_ws, size_t ws_size,
                              hipStream_t stream) {
  const float* hs = (const float*)d_in[0];
  const float* Wq = (const float*)d_in[1];
  const float* Wk = (const float*)d_in[2];
  const float* Wv = (const float*)d_in[3];
  const float* Wo = (const float*)d_in[4];

  const size_t NEL = (size_t)Mz * Hz;   // 8388608
  const size_t WEL = (size_t)Hz * Hz;   // 1048576

  unsigned short* p = (unsigned short*)d_ws;
  unsigned short* hs_bf = p; p += NEL;
  unsigned short* Wq_bf = p; p += WEL;
  unsigned short* Wk_bf = p; p += WEL;
  unsigned short* Wv_bf = p; p += WEL;
  unsigned short* Wo_bf = p; p += WEL;
  unsigned short* Qb    = p; p += NEL;
  unsigned short* Kb    = p; p += NEL;
  unsigned short* Vtb   = p; p += NEL;
  unsigned short* Ob    = hs_bf;        // alias: hs_bf dead after QKV GEMM

  cvt_kernel<<<2048, 256, 0, stream>>>(hs, hs_bf, (int)NEL);
  cvt4_kernel<<<dim3(512, 4), 256, 0, stream>>>(Wq, Wk, Wv, Wo,
                                                Wq_bf, Wk_bf, Wv_bf, Wo_bf);

  const float qscale = 0.08838834764831845f * 1.44269504088896340736f; // 1/sqrt(128)*log2(e)
  gemm_qkv<<<dim3(Mz / 128, Hz / 128, 3), 256, 0, stream>>>(
      hs_bf, Wq_bf, Wk_bf, Wv_bf, Qb, Kb, Vtb, qscale);

  attn_fwd<<<1024, 256, 0, stream>>>(Qb, Kb, Vtb, Ob);

  gemm_out<<<dim3(Mz / 128, Hz / 128), 256, 0, stream>>>(Ob, Wo_bf, (float*)d_out);
}

// Round 7
// 339.450 us; speedup vs baseline: 2.1458x; 1.5982x over previous
//
#include <hip/hip_runtime.h>
#include <stdint.h>

// Problem constants
#define Bz  4
#define Sz  2048
#define Hz  1024
#define NHz 8
#define HDz 128
#define Mz  (Bz*Sz)          // 8192 rows for all GEMMs

typedef __attribute__((ext_vector_type(8))) short bf16x8;   // 8 bf16 = 4 VGPRs
typedef __attribute__((ext_vector_type(4))) float f32x4;

__device__ __forceinline__ unsigned short f2bf(float x) {
  union { float f; unsigned int u; } c; c.f = x;
  unsigned int u = c.u;
  return (unsigned short)((u + 0x7FFFu + ((u >> 16) & 1u)) >> 16);  // RNE
}

__device__ __forceinline__ void gl2lds16(const unsigned short* g, unsigned short* l) {
  __builtin_amdgcn_global_load_lds(
      (const __attribute__((address_space(1))) unsigned int*)g,
      (__attribute__((address_space(3))) unsigned int*)l, 16, 0, 0);
}

// ---------------------------------------------------------------- cvt f32->bf16
__global__ __launch_bounds__(256)
void cvt_kernel(const float* __restrict__ in, unsigned short* __restrict__ out, int n) {
  const int n4 = n >> 2;
  for (int i = blockIdx.x * blockDim.x + threadIdx.x; i < n4; i += gridDim.x * blockDim.x) {
    float4 v = ((const float4*)in)[i];
    ushort4 o;
    o.x = f2bf(v.x); o.y = f2bf(v.y); o.z = f2bf(v.z); o.w = f2bf(v.w);
    ((ushort4*)out)[i] = o;
  }
}

__global__ __launch_bounds__(256)
void cvt4_kernel(const float* __restrict__ w0, const float* __restrict__ w1,
                 const float* __restrict__ w2, const float* __restrict__ w3,
                 unsigned short* __restrict__ o0, unsigned short* __restrict__ o1,
                 unsigned short* __restrict__ o2, unsigned short* __restrict__ o3) {
  const int which = blockIdx.y;
  const float* in = (which == 0) ? w0 : (which == 1) ? w1 : (which == 2) ? w2 : w3;
  unsigned short* out = (which == 0) ? o0 : (which == 1) ? o1 : (which == 2) ? o2 : o3;
  const int n4 = (Hz * Hz) >> 2;
  for (int i = blockIdx.x * blockDim.x + threadIdx.x; i < n4; i += gridDim.x * blockDim.x) {
    float4 v = ((const float4*)in)[i];
    ushort4 o;
    o.x = f2bf(v.x); o.y = f2bf(v.y); o.z = f2bf(v.z); o.w = f2bf(v.w);
    ((ushort4*)out)[i] = o;
  }
}

// ---------------------------------------------------------------- GEMM cores
// C = A * Bw^T, 128x128 tile, BK=64, 4 waves. Shared by fused-QKV and Wo kernels.
#define GEMM_PROLOG()                                                           \
  __shared__ __align__(16) unsigned short Asm[128 * 64];                        \
  __shared__ __align__(16) unsigned short Bsm[128 * 64];                        \
  const int tid = threadIdx.x;                                                  \
  const int w  = tid >> 6, l = tid & 63;                                        \
  const int lc = l & 15,  lg = l >> 4;                                          \
  const int wr = w >> 1,  wc = w & 1;                                           \
  const int bm = blockIdx.x * 128;                                              \
  const int bn = blockIdx.y * 128;                                              \
  f32x4 acc[4][4];                                                              \
  _Pragma("unroll")                                                             \
  for (int i = 0; i < 4; i++)                                                   \
    _Pragma("unroll")                                                           \
    for (int j = 0; j < 4; j++) acc[i][j] = (f32x4){0.f, 0.f, 0.f, 0.f};        \
  const int srow = w * 32 + (l >> 3);                                           \
  const int scol = (l & 7) * 8;                                                 \
  for (int kt = 0; kt < 16; kt++) {                                             \
    const int k0 = kt * 64;                                                     \
    __syncthreads();                                                            \
    _Pragma("unroll")                                                           \
    for (int i = 0; i < 4; i++) {                                               \
      gl2lds16(A  + (size_t)(bm + srow + i * 8) * Hz + k0 + scol,               \
               &Asm[(w * 32 + i * 8) * 64]);                                    \
      gl2lds16(Bw + (size_t)(bn + srow + i * 8) * Hz + k0 + scol,               \
               &Bsm[(w * 32 + i * 8) * 64]);                                    \
    }                                                                           \
    __syncthreads();                                                            \
    _Pragma("unroll")                                                           \
    for (int kk = 0; kk < 2; kk++) {                                            \
      bf16x8 af[4], bf[4];                                                      \
      _Pragma("unroll")                                                         \
      for (int t = 0; t < 4; t++) {                                             \
        af[t] = *(const bf16x8*)&Asm[(wr*64 + t*16 + lc)*64 + kk*32 + lg*8];    \
        bf[t] = *(const bf16x8*)&Bsm[(wc*64 + t*16 + lc)*64 + kk*32 + lg*8];    \
      }                                                                         \
      _Pragma("unroll")                                                         \
      for (int mt = 0; mt < 4; mt++)                                            \
        _Pragma("unroll")                                                       \
        for (int nt = 0; nt < 4; nt++)                                          \
          acc[mt][nt] = __builtin_amdgcn_mfma_f32_16x16x32_bf16(                \
              af[mt], bf[nt], acc[mt][nt], 0, 0, 0);                            \
    }                                                                           \
  }

// fused Q/K/V projection: blockIdx.z selects weight & destination
__global__ __launch_bounds__(256)
void gemm_qkv(const unsigned short* __restrict__ A,
              const unsigned short* __restrict__ W0,
              const unsigned short* __restrict__ W1,
              const unsigned short* __restrict__ W2,
              unsigned short* __restrict__ Qo,
              unsigned short* __restrict__ Ko,
              unsigned short* __restrict__ Vto, float qscale)
{
  const int z = blockIdx.z;
  const unsigned short* Bw = (z == 0) ? W0 : (z == 1) ? W1 : W2;
  const float alpha = (z == 0) ? qscale : 1.0f;
  GEMM_PROLOG()

#pragma unroll
  for (int mt = 0; mt < 4; mt++) {
#pragma unroll
    for (int nt = 0; nt < 4; nt++) {
      const int row0 = bm + wr * 64 + mt * 16 + lg * 4;
      const int col  = bn + wc * 64 + nt * 16 + lc;
      if (z == 2) {
        // V^T layout: [(b*NH+nh)*HD + hd][S]
        ushort4 pk;
        pk.x = f2bf(acc[mt][nt][0]);
        pk.y = f2bf(acc[mt][nt][1]);
        pk.z = f2bf(acc[mt][nt][2]);
        pk.w = f2bf(acc[mt][nt][3]);
        const size_t idx = ((size_t)((row0 >> 11) << 10) + col) * Sz + (row0 & 2047);
        *(ushort4*)&Vto[idx] = pk;
      } else {
        unsigned short* C = (z == 0) ? Qo : Ko;
#pragma unroll
        for (int r = 0; r < 4; r++)
          C[(size_t)(row0 + r) * Hz + col] = f2bf(acc[mt][nt][r] * alpha);
      }
    }
  }
}

// output projection: f32 out
__global__ __launch_bounds__(256)
void gemm_out(const unsigned short* __restrict__ A,
              const unsigned short* __restrict__ Bw,
              float* __restrict__ C)
{
  GEMM_PROLOG()
#pragma unroll
  for (int mt = 0; mt < 4; mt++)
#pragma unroll
    for (int nt = 0; nt < 4; nt++) {
      const int row0 = bm + wr * 64 + mt * 16 + lg * 4;
      const int col  = bn + wc * 64 + nt * 16 + lc;
#pragma unroll
      for (int r = 0; r < 4; r++)
        C[(size_t)(row0 + r) * Hz + col] = acc[mt][nt][r];
    }
}

// ---------------------------------------------------------------- flash attention
// Round-3 structure (measured best: 177us): 4 waves, 128 q/block, K dbuf LDS,
// V staged in LDS (mid-iter barrier), P via per-wave LDS, no setprio.
// Delta this round: lrow cross-lane reduction DEFERRED to epilogue
// (accumulate per-lane partials; rescale factor is row-uniform so partials
// stay consistent). Removes 32 shfl/iter from the VALU-bound softmax phase.
__global__ __launch_bounds__(256, 2)
void attn_fwd(const unsigned short* __restrict__ Q,
              const unsigned short* __restrict__ K,
              const unsigned short* __restrict__ Vt,
              unsigned short* __restrict__ O)
{
  // bijective XCD swizzle: 512 blocks -> 64 consecutive wg per XCD (4 heads/XCD)
  const int bid = blockIdx.x;
  const int wg  = (bid & 7) * 64 + (bid >> 3);
  const int qb  = wg & 15;               // q-block: rows qb*128..+127
  const int bh  = wg >> 4;               // 0..31
  const int b = bh >> 3, nh = bh & 7;
  const int w = threadIdx.x >> 6, l = threadIdx.x & 63;
  const int lc = l & 15, lg = l >> 4;

  __shared__ __align__(16) unsigned short Ksm[2][64 * 128]; // 32 KB, dbuf
  __shared__ __align__(16) unsigned short Vsm[128 * 64];    // 16 KB
  __shared__ __align__(16) unsigned short Psm[4][16 * 64];  //  8 KB per-wave

  bf16x8 qf[2][4];
#pragma unroll
  for (int mt = 0; mt < 2; mt++)
#pragma unroll
    for (int ks = 0; ks < 4; ks++)
      qf[mt][ks] = *(const bf16x8*)(Q + ((size_t)b * Sz + qb * 128 + w * 32 + mt * 16 + lc) * Hz
                                      + nh * HDz + ks * 32 + lg * 8);

  const unsigned short* Kbase = K  + (size_t)b * Sz * Hz + nh * HDz;
  const unsigned short* Vbase = Vt + (size_t)bh * HDz * Sz;

  f32x4 acc[2][8];
#pragma unroll
  for (int mt = 0; mt < 2; mt++)
#pragma unroll
    for (int i = 0; i < 8; i++) acc[mt][i] = (f32x4){0.f, 0.f, 0.f, 0.f};
  float mrow[2][4], lrow[2][4];
#pragma unroll
  for (int mt = 0; mt < 2; mt++)
#pragma unroll
    for (int r = 0; r < 4; r++) { mrow[mt][r] = -1e30f; lrow[mt][r] = 0.f; }

  // K tile [64 s][128 d], V tile [128 hd][64 s]: linear LDS dest +
  // involution-swizzled global source
  #define STAGE_K(BUF, KT) {                                                          \
    _Pragma("unroll")                                                                 \
    for (int i = 0; i < 4; i++) {                                                     \
      const int r = w * 16 + i * 4 + (l >> 4);                                        \
      gl2lds16(Kbase + (size_t)((KT) * 64 + r) * Hz + (((l & 15) ^ (r & 7)) * 8),     \
               &Ksm[BUF][(w * 16 + i * 4) * 128]);                                    \
    } }
  #define STAGE_V(KT) {                                                               \
    _Pragma("unroll")                                                                 \
    for (int i = 0; i < 4; i++) {                                                     \
      const int r = w * 32 + i * 8 + (l >> 3);                                        \
      gl2lds16(Vbase + (size_t)r * Sz + (KT) * 64 + (((l & 7) ^ (r & 7)) * 8),        \
               &Vsm[(w * 32 + i * 8) * 64]);                                          \
    } }

  int cur = 0;
  STAGE_K(0, 0);
  __syncthreads();   // K[0] resident

  for (int kt = 0; kt < Sz / 64; kt++) {
    // ---- issue async stages: V for THIS tile, K for NEXT tile
    STAGE_V(kt);
    if (kt < Sz / 64 - 1) STAGE_K(cur ^ 1, kt + 1);

    // ---- QK^T from Ksm[cur] (swizzled reads)
    f32x4 s[2][4];
#pragma unroll
    for (int mt = 0; mt < 2; mt++)
#pragma unroll
      for (int nt = 0; nt < 4; nt++) s[mt][nt] = (f32x4){0.f, 0.f, 0.f, 0.f};
#pragma unroll
    for (int ks = 0; ks < 4; ks++) {
#pragma unroll
      for (int nt = 0; nt < 4; nt++) {
        bf16x8 kf = *(const bf16x8*)&Ksm[cur][(nt * 16 + lc) * 128 + (((ks * 4 + lg) ^ (lc & 7)) * 8)];
#pragma unroll
        for (int mt = 0; mt < 2; mt++)
          s[mt][nt] = __builtin_amdgcn_mfma_f32_16x16x32_bf16(qf[mt][ks], kf, s[mt][nt], 0, 0, 0);
      }
    }

    // ---- online softmax (exp2-space, defer-max THR=8, lrow kept as
    //      per-lane PARTIAL sums — cross-lane reduce deferred to epilogue)
#pragma unroll
    for (int mt = 0; mt < 2; mt++) {
#pragma unroll
      for (int r = 0; r < 4; r++) {
        float tm = fmaxf(fmaxf(s[mt][0][r], s[mt][1][r]), fmaxf(s[mt][2][r], s[mt][3][r]));
        tm = fmaxf(tm, __shfl_xor(tm, 1));
        tm = fmaxf(tm, __shfl_xor(tm, 2));
        tm = fmaxf(tm, __shfl_xor(tm, 4));
        tm = fmaxf(tm, __shfl_xor(tm, 8));
        if (tm > mrow[mt][r] + 8.0f) {
          const float sc = exp2f(mrow[mt][r] - tm);   // row-uniform
          mrow[mt][r] = tm;
          lrow[mt][r] *= sc;
#pragma unroll
          for (int nt = 0; nt < 8; nt++) acc[mt][nt][r] *= sc;
        }
        float rs = 0.f;
#pragma unroll
        for (int nt = 0; nt < 4; nt++) {
          float p = exp2f(s[mt][nt][r] - mrow[mt][r]);
          s[mt][nt][r] = p;
          rs += p;
        }
        lrow[mt][r] += rs;    // partial only; no shuffles here
      }
    }

    // ---- P -> per-wave LDS (swizzled) -> A-fragments
    bf16x8 pf[2][2];
#pragma unroll
    for (int mt = 0; mt < 2; mt++) {
#pragma unroll
      for (int nt = 0; nt < 4; nt++)
#pragma unroll
        for (int r = 0; r < 4; r++) {
          const int row = lg * 4 + r;
          const int ch  = (nt * 2 + (lc >> 3)) ^ (row & 7);
          Psm[w][row * 64 + ch * 8 + (lc & 7)] = f2bf(s[mt][nt][r]);
        }
#pragma unroll
      for (int kk = 0; kk < 2; kk++)
        pf[mt][kk] = *(const bf16x8*)&Psm[w][lc * 64 + (((kk * 4 + lg) ^ (lc & 7)) * 8)];
    }

    __syncthreads();   // V[kt] (and K[kt+1]) resident; all waves past QK^T reads

    // ---- PV from Vsm (swizzled reads), vf shared across m
#pragma unroll
    for (int kk = 0; kk < 2; kk++) {
#pragma unroll
      for (int nt = 0; nt < 8; nt++) {
        bf16x8 vf = *(const bf16x8*)&Vsm[(nt * 16 + lc) * 64 + (((kk * 4 + lg) ^ (lc & 7)) * 8)];
        acc[0][nt] = __builtin_amdgcn_mfma_f32_16x16x32_bf16(pf[0][kk], vf, acc[0][nt], 0, 0, 0);
        acc[1][nt] = __builtin_amdgcn_mfma_f32_16x16x32_bf16(pf[1][kk], vf, acc[1][nt], 0, 0, 0);
      }
    }

    __syncthreads();   // Vsm / Ksm[cur] safe to overwrite next iter
    cur ^= 1;
  }

  // ---- epilogue: one cross-lane lrow reduction, then normalize & store
#pragma unroll
  for (int mt = 0; mt < 2; mt++) {
    float inv[4];
#pragma unroll
    for (int r = 0; r < 4; r++) {
      float t = lrow[mt][r];
      t += __shfl_xor(t, 1);
      t += __shfl_xor(t, 2);
      t += __shfl_xor(t, 4);
      t += __shfl_xor(t, 8);
      inv[r] = 1.0f / t;
    }
#pragma unroll
    for (int nt = 0; nt < 8; nt++)
#pragma unroll
      for (int r = 0; r < 4; r++) {
        const size_t row = (size_t)b * Sz + qb * 128 + w * 32 + mt * 16 + lg * 4 + r;
        O[row * Hz + nh * HDz + nt * 16 + lc] = f2bf(acc[mt][nt][r] * inv[r]);
      }
  }
}

// ---------------------------------------------------------------- launch
extern "C" void kernel_launch(void* const* d_in, const int* in_sizes, int n_in,
                              void* d_out, int out_size, void* d_ws, size_t ws_size,
                              hipStream_t stream) {
  const float* hs = (const float*)d_in[0];
  const float* Wq = (const float*)d_in[1];
  const float* Wk = (const float*)d_in[2];
  const float* Wv = (const float*)d_in[3];
  const float* Wo = (const float*)d_in[4];

  const size_t NEL = (size_t)Mz * Hz;   // 8388608
  const size_t WEL = (size_t)Hz * Hz;   // 1048576

  unsigned short* p = (unsigned short*)d_ws;
  unsigned short* hs_bf = p; p += NEL;
  unsigned short* Wq_bf = p; p += WEL;
  unsigned short* Wk_bf = p; p += WEL;
  unsigned short* Wv_bf = p; p += WEL;
  unsigned short* Wo_bf = p; p += WEL;
  unsigned short* Qb    = p; p += NEL;
  unsigned short* Kb    = p; p += NEL;
  unsigned short* Vtb   = p; p += NEL;
  unsigned short* Ob    = hs_bf;        // alias: hs_bf dead after QKV GEMM

  cvt_kernel<<<2048, 256, 0, stream>>>(hs, hs_bf, (int)NEL);
  cvt4_kernel<<<dim3(512, 4), 256, 0, stream>>>(Wq, Wk, Wv, Wo,
                                                Wq_bf, Wk_bf, Wv_bf, Wo_bf);

  const float qscale = 0.08838834764831845f * 1.44269504088896340736f; // 1/sqrt(128)*log2(e)
  gemm_qkv<<<dim3(Mz / 128, Hz / 128, 3), 256, 0, stream>>>(
      hs_bf, Wq_bf, Wk_bf, Wv_bf, Qb, Kb, Vtb, qscale);

  attn_fwd<<<512, 256, 0, stream>>>(Qb, Kb, Vtb, Ob);

  gemm_out<<<dim3(Mz / 128, Hz / 128), 256, 0, stream>>>(Ob, Wo_bf, (float*)d_out);
}

// Round 9
// 295.764 us; speedup vs baseline: 2.4628x; 1.1477x over previous
//
#include <hip/hip_runtime.h>
#include <stdint.h>

// Problem constants
#define Bz  4
#define Sz  2048
#define Hz  1024
#define NHz 8
#define HDz 128
#define Mz  (Bz*Sz)          // 8192 rows for all GEMMs

typedef __attribute__((ext_vector_type(8))) short bf16x8;   // 8 bf16 = 4 VGPRs
typedef __attribute__((ext_vector_type(4))) float f32x4;
typedef __attribute__((ext_vector_type(16))) float f32x16;

__device__ __forceinline__ unsigned short f2bf(float x) {
  union { float f; unsigned int u; } c; c.f = x;
  unsigned int u = c.u;
  return (unsigned short)((u + 0x7FFFu + ((u >> 16) & 1u)) >> 16);  // RNE
}

// v_cvt_pk_bf16_f32: dst = {bf16(lo), bf16(hi)<<16}  (T12 recipe)
__device__ __forceinline__ unsigned cvtpk(float lo, float hi_) {
  unsigned r;
  asm("v_cvt_pk_bf16_f32 %0, %1, %2" : "=v"(r) : "v"(lo), "v"(hi_));
  return r;
}

__device__ __forceinline__ void gl2lds16(const unsigned short* g, unsigned short* l) {
  __builtin_amdgcn_global_load_lds(
      (const __attribute__((address_space(1))) unsigned int*)g,
      (__attribute__((address_space(3))) unsigned int*)l, 16, 0, 0);
}

// ---------------------------------------------------------------- cvt f32->bf16
__global__ __launch_bounds__(256)
void cvt_kernel(const float* __restrict__ in, unsigned short* __restrict__ out, int n) {
  const int n4 = n >> 2;
  for (int i = blockIdx.x * blockDim.x + threadIdx.x; i < n4; i += gridDim.x * blockDim.x) {
    float4 v = ((const float4*)in)[i];
    ushort4 o;
    o.x = f2bf(v.x); o.y = f2bf(v.y); o.z = f2bf(v.z); o.w = f2bf(v.w);
    ((ushort4*)out)[i] = o;
  }
}

__global__ __launch_bounds__(256)
void cvt4_kernel(const float* __restrict__ w0, const float* __restrict__ w1,
                 const float* __restrict__ w2, const float* __restrict__ w3,
                 unsigned short* __restrict__ o0, unsigned short* __restrict__ o1,
                 unsigned short* __restrict__ o2, unsigned short* __restrict__ o3) {
  const int which = blockIdx.y;
  const float* in = (which == 0) ? w0 : (which == 1) ? w1 : (which == 2) ? w2 : w3;
  unsigned short* out = (which == 0) ? o0 : (which == 1) ? o1 : (which == 2) ? o2 : o3;
  const int n4 = (Hz * Hz) >> 2;
  for (int i = blockIdx.x * blockDim.x + threadIdx.x; i < n4; i += gridDim.x * blockDim.x) {
    float4 v = ((const float4*)in)[i];
    ushort4 o;
    o.x = f2bf(v.x); o.y = f2bf(v.y); o.z = f2bf(v.z); o.w = f2bf(v.w);
    ((ushort4*)out)[i] = o;
  }
}

// ---------------------------------------------------------------- GEMM cores
// C = A * Bw^T, 128x128 tile, BK=64, 4 waves. Shared by fused-QKV and Wo kernels.
#define GEMM_PROLOG()                                                           \
  __shared__ __align__(16) unsigned short Asm[128 * 64];                        \
  __shared__ __align__(16) unsigned short Bsm[128 * 64];                        \
  const int tid = threadIdx.x;                                                  \
  const int w  = tid >> 6, l = tid & 63;                                        \
  const int lc = l & 15,  lg = l >> 4;                                          \
  const int wr = w >> 1,  wc = w & 1;                                           \
  const int bm = blockIdx.x * 128;                                              \
  const int bn = blockIdx.y * 128;                                              \
  f32x4 acc[4][4];                                                              \
  _Pragma("unroll")                                                             \
  for (int i = 0; i < 4; i++)                                                   \
    _Pragma("unroll")                                                           \
    for (int j = 0; j < 4; j++) acc[i][j] = (f32x4){0.f, 0.f, 0.f, 0.f};        \
  const int srow = w * 32 + (l >> 3);                                           \
  const int scol = (l & 7) * 8;                                                 \
  for (int kt = 0; kt < 16; kt++) {                                             \
    const int k0 = kt * 64;                                                     \
    __syncthreads();                                                            \
    _Pragma("unroll")                                                           \
    for (int i = 0; i < 4; i++) {                                               \
      gl2lds16(A  + (size_t)(bm + srow + i * 8) * Hz + k0 + scol,               \
               &Asm[(w * 32 + i * 8) * 64]);                                    \
      gl2lds16(Bw + (size_t)(bn + srow + i * 8) * Hz + k0 + scol,               \
               &Bsm[(w * 32 + i * 8) * 64]);                                    \
    }                                                                           \
    __syncthreads();                                                            \
    _Pragma("unroll")                                                           \
    for (int kk = 0; kk < 2; kk++) {                                            \
      bf16x8 af[4], bf[4];                                                      \
      _Pragma("unroll")                                                         \
      for (int t = 0; t < 4; t++) {                                             \
        af[t] = *(const bf16x8*)&Asm[(wr*64 + t*16 + lc)*64 + kk*32 + lg*8];    \
        bf[t] = *(const bf16x8*)&Bsm[(wc*64 + t*16 + lc)*64 + kk*32 + lg*8];    \
      }                                                                         \
      _Pragma("unroll")                                                         \
      for (int mt = 0; mt < 4; mt++)                                            \
        _Pragma("unroll")                                                       \
        for (int nt = 0; nt < 4; nt++)                                          \
          acc[mt][nt] = __builtin_amdgcn_mfma_f32_16x16x32_bf16(                \
              af[mt], bf[nt], acc[mt][nt], 0, 0, 0);                            \
    }                                                                           \
  }

// fused Q/K/V projection: blockIdx.z selects weight & destination
__global__ __launch_bounds__(256)
void gemm_qkv(const unsigned short* __restrict__ A,
              const unsigned short* __restrict__ W0,
              const unsigned short* __restrict__ W1,
              const unsigned short* __restrict__ W2,
              unsigned short* __restrict__ Qo,
              unsigned short* __restrict__ Ko,
              unsigned short* __restrict__ Vto, float qscale)
{
  const int z = blockIdx.z;
  const unsigned short* Bw = (z == 0) ? W0 : (z == 1) ? W1 : W2;
  const float alpha = (z == 0) ? qscale : 1.0f;
  GEMM_PROLOG()

#pragma unroll
  for (int mt = 0; mt < 4; mt++) {
#pragma unroll
    for (int nt = 0; nt < 4; nt++) {
      const int row0 = bm + wr * 64 + mt * 16 + lg * 4;
      const int col  = bn + wc * 64 + nt * 16 + lc;
      if (z == 2) {
        // V^T layout: [(b*NH+nh)*HD + hd][S]
        ushort4 pk;
        pk.x = f2bf(acc[mt][nt][0]);
        pk.y = f2bf(acc[mt][nt][1]);
        pk.z = f2bf(acc[mt][nt][2]);
        pk.w = f2bf(acc[mt][nt][3]);
        const size_t idx = ((size_t)((row0 >> 11) << 10) + col) * Sz + (row0 & 2047);
        *(ushort4*)&Vto[idx] = pk;
      } else {
        unsigned short* C = (z == 0) ? Qo : Ko;
#pragma unroll
        for (int r = 0; r < 4; r++)
          C[(size_t)(row0 + r) * Hz + col] = f2bf(acc[mt][nt][r] * alpha);
      }
    }
  }
}

// output projection: f32 out
__global__ __launch_bounds__(256)
void gemm_out(const unsigned short* __restrict__ A,
              const unsigned short* __restrict__ Bw,
              float* __restrict__ C)
{
  GEMM_PROLOG()
#pragma unroll
  for (int mt = 0; mt < 4; mt++)
#pragma unroll
    for (int nt = 0; nt < 4; nt++) {
      const int row0 = bm + wr * 64 + mt * 16 + lg * 4;
      const int col  = bn + wc * 64 + nt * 16 + lc;
#pragma unroll
      for (int r = 0; r < 4; r++)
        C[(size_t)(row0 + r) * Hz + col] = acc[mt][nt][r];
    }
}

// ---------------------------------------------------------------- flash attention
// 32x32 swapped-QK^T + in-register P (m214/T12 style), on the verified round-3/7
// staging skeleton: 4 waves x 32 q-rows, K dbuf LDS + V LDS, involution swizzles.
// S^T = mfma32(K,Q): lane owns q-col (lane&31); row-max = in-lane tree + 1
// shfl_xor(32). P -> bf16 via v_cvt_pk + 1 shfl_xor(32) partner exchange ->
// PV A-frags in registers (Psm deleted). LDS 48KB.
__global__ __launch_bounds__(256, 2)
void attn_fwd(const unsigned short* __restrict__ Q,
              const unsigned short* __restrict__ K,
              const unsigned short* __restrict__ Vt,
              unsigned short* __restrict__ O)
{
  // bijective XCD swizzle: 512 blocks -> 64 consecutive wg per XCD (4 heads/XCD)
  const int bid = blockIdx.x;
  const int wg  = (bid & 7) * 64 + (bid >> 3);
  const int qb  = wg & 15;               // q-block: rows qb*128..+127
  const int bh  = wg >> 4;               // 0..31
  const int b = bh >> 3, nh = bh & 7;
  const int w = threadIdx.x >> 6, l = threadIdx.x & 63;
  const int l31 = l & 31, hi = l >> 5;

  __shared__ __align__(16) unsigned short Ksm[2][64 * 128]; // 32 KB, dbuf
  __shared__ __align__(16) unsigned short Vsm[128 * 64];    // 16 KB

  // Q fragments: B-operand cols q = w*32 + l31, 8 ks-slices of 16 d each
  bf16x8 qf[8];
#pragma unroll
  for (int ks = 0; ks < 8; ks++)
    qf[ks] = *(const bf16x8*)(Q + ((size_t)b * Sz + qb * 128 + w * 32 + l31) * Hz
                                + nh * HDz + ks * 16 + hi * 8);

  const unsigned short* Kbase = K  + (size_t)b * Sz * Hz + nh * HDz;
  const unsigned short* Vbase = Vt + (size_t)bh * HDz * Sz;

  f32x16 acc[4];
#pragma unroll
  for (int d = 0; d < 4; d++)
#pragma unroll
    for (int i = 0; i < 16; i++) acc[d][i] = 0.f;
  float mrow = -3.0e38f, lrowp = 0.f;   // per-lane: q-row = w*32+l31, k-half hi

  union PA { unsigned wd[4]; bf16x8 v; };

  #define STAGE_K(BUF, KT) {                                                          \
    _Pragma("unroll")                                                                 \
    for (int i = 0; i < 4; i++) {                                                     \
      const int r = w * 16 + i * 4 + (l >> 4);                                        \
      gl2lds16(Kbase + (size_t)((KT) * 64 + r) * Hz + (((l & 15) ^ (r & 7)) * 8),     \
               &Ksm[BUF][(w * 16 + i * 4) * 128]);                                    \
    } }
  #define STAGE_V(KT) {                                                               \
    _Pragma("unroll")                                                                 \
    for (int i = 0; i < 4; i++) {                                                     \
      const int r = w * 32 + i * 8 + (l >> 3);                                        \
      gl2lds16(Vbase + (size_t)r * Sz + (KT) * 64 + (((l & 7) ^ (r & 7)) * 8),        \
               &Vsm[(w * 32 + i * 8) * 64]);                                          \
    } }

  int cur = 0;
  STAGE_K(0, 0);
  __syncthreads();   // K[0] resident

  for (int kt = 0; kt < Sz / 64; kt++) {
    // ---- issue async stages: V for THIS tile, K for NEXT tile
    STAGE_V(kt);
    if (kt < Sz / 64 - 1) STAGE_K(cur ^ 1, kt + 1);

    // ---- QK^T (swapped): st[n32] = S^T for k-rows n32*32+crow, q-col = l31
    f32x16 st[2];
#pragma unroll
    for (int i = 0; i < 16; i++) { st[0][i] = 0.f; st[1][i] = 0.f; }
#pragma unroll
    for (int ks = 0; ks < 8; ks++) {
      bf16x8 kf0 = *(const bf16x8*)&Ksm[cur][(l31) * 128 + (((ks * 2 + hi) ^ (l31 & 7)) * 8)];
      st[0] = __builtin_amdgcn_mfma_f32_32x32x16_bf16(kf0, qf[ks], st[0], 0, 0, 0);
      bf16x8 kf1 = *(const bf16x8*)&Ksm[cur][(32 + l31) * 128 + (((ks * 2 + hi) ^ (l31 & 7)) * 8)];
      st[1] = __builtin_amdgcn_mfma_f32_32x32x16_bf16(kf1, qf[ks], st[1], 0, 0, 0);
    }

    // ---- row-max: in-lane tree over 32 values + 1 partner swap
    float t16[16];
#pragma unroll
    for (int i = 0; i < 16; i++) t16[i] = fmaxf(st[0][i], st[1][i]);
#pragma unroll
    for (int s = 8; s > 0; s >>= 1)
#pragma unroll
      for (int i = 0; i < s; i++) t16[i] = fmaxf(t16[i], t16[i + s]);
    const float tm = fmaxf(t16[0], __shfl_xor(t16[0], 32));

    // ---- defer-max (THR=8): rescale acc only when a row's max grows a lot
    float sc = 1.0f;
    const bool trig = tm > mrow + 8.0f;
    if (trig) { sc = exp2f(mrow - tm); mrow = tm; lrowp *= sc; }
    if (__any(trig)) {
#pragma unroll
      for (int r = 0; r < 16; r++) {
        const float scr = __shfl(sc, (r & 3) + 8 * (r >> 2) + 4 * hi);
#pragma unroll
        for (int d = 0; d < 4; d++) acc[d][r] *= scr;
      }
    }

    // ---- P = exp2(S - m) in-place; per-lane partial row-sum
    float ps = 0.f;
#pragma unroll
    for (int n = 0; n < 2; n++)
#pragma unroll
      for (int i = 0; i < 16; i++) {
        const float p = exp2f(st[n][i] - mrow);
        st[n][i] = p;
        ps += p;
      }
    lrowp += ps;

    // ---- P -> bf16 PV A-fragments in registers (cvt_pk + partner exchange)
    PA pa[4];
#pragma unroll
    for (int n = 0; n < 2; n++) {
      unsigned Wp[8];
#pragma unroll
      for (int m = 0; m < 4; m++) {
        Wp[m * 2 + 0] = cvtpk(st[n][4 * m + 0], st[n][4 * m + 1]);
        Wp[m * 2 + 1] = cvtpk(st[n][4 * m + 2], st[n][4 * m + 3]);
      }
#pragma unroll
      for (int ks2 = 0; ks2 < 2; ks2++) {
#pragma unroll
        for (int h = 0; h < 2; h++) {
          const unsigned a0 = Wp[(2 * ks2) * 2 + h];      // reg-group m = 2ks2
          const unsigned a1 = Wp[(2 * ks2 + 1) * 2 + h];  // reg-group m = 2ks2+1
          const unsigned own  = hi ? a1 : a0;
          const unsigned send = hi ? a0 : a1;
          const unsigned part = __shfl_xor(send, 32);
          pa[n * 2 + ks2].wd[0 + h] = hi ? part : own;    // word jh=0
          pa[n * 2 + ks2].wd[2 + h] = hi ? own : part;    // word jh=1
        }
      }
    }

    __syncthreads();   // V[kt] (and K[kt+1]) resident; all waves past QK^T reads

    // ---- PV: acc[d-block] += P[32q x 16k] * V[16k x 32d], 16 mfma32
#pragma unroll
    for (int t = 0; t < 4; t++)
#pragma unroll
      for (int d = 0; d < 4; d++) {
        bf16x8 vf = *(const bf16x8*)&Vsm[(d * 32 + l31) * 64 + (((t * 2 + hi) ^ (l31 & 7)) * 8)];
        acc[d] = __builtin_amdgcn_mfma_f32_32x32x16_bf16(pa[t].v, vf, acc[d], 0, 0, 0);
      }

    __syncthreads();   // Vsm / Ksm[cur] safe to overwrite next iter
    cur ^= 1;
  }

  // ---- epilogue: reduce partner halves, redistribute inv, store
  const float lsum = lrowp + __shfl_xor(lrowp, 32);
  const float inv = 1.0f / lsum;     // valid per q-row at lanes 0..31 (and dup 32..63)
#pragma unroll
  for (int r = 0; r < 16; r++) {
    const float ir = __shfl(inv, (r & 3) + 8 * (r >> 2) + 4 * hi);
    const size_t row = (size_t)b * Sz + qb * 128 + w * 32 + (r & 3) + 8 * (r >> 2) + 4 * hi;
#pragma unroll
    for (int d = 0; d < 4; d++)
      O[row * Hz + nh * HDz + d * 32 + l31] = f2bf(acc[d][r] * ir);
  }
}

// ---------------------------------------------------------------- launch
extern "C" void kernel_launch(void* const* d_in, const int* in_sizes, int n_in,
                              void* d_out, int out_size, void* d_ws, size_t ws_size,
                              hipStream_t stream) {
  const float* hs = (const float*)d_in[0];
  const float* Wq = (const float*)d_in[1];
  const float* Wk = (const float*)d_in[2];
  const float* Wv = (const float*)d_in[3];
  const float* Wo = (const float*)d_in[4];

  const size_t NEL = (size_t)Mz * Hz;   // 8388608
  const size_t WEL = (size_t)Hz * Hz;   // 1048576

  unsigned short* p = (unsigned short*)d_ws;
  unsigned short* hs_bf = p; p += NEL;
  unsigned short* Wq_bf = p; p += WEL;
  unsigned short* Wk_bf = p; p += WEL;
  unsigned short* Wv_bf = p; p += WEL;
  unsigned short* Wo_bf = p; p += WEL;
  unsigned short* Qb    = p; p += NEL;
  unsigned short* Kb    = p; p += NEL;
  unsigned short* Vtb   = p; p += NEL;
  unsigned short* Ob    = hs_bf;        // alias: hs_bf dead after QKV GEMM

  cvt_kernel<<<2048, 256, 0, stream>>>(hs, hs_bf, (int)NEL);
  cvt4_kernel<<<dim3(512, 4), 256, 0, stream>>>(Wq, Wk, Wv, Wo,
                                                Wq_bf, Wk_bf, Wv_bf, Wo_bf);

  const float qscale = 0.08838834764831845f * 1.44269504088896340736f; // 1/sqrt(128)*log2(e)
  gemm_qkv<<<dim3(Mz / 128, Hz / 128, 3), 256, 0, stream>>>(
      hs_bf, Wq_bf, Wk_bf, Wv_bf, Qb, Kb, Vtb, qscale);

  attn_fwd<<<512, 256, 0, stream>>>(Qb, Kb, Vtb, Ob);

  gemm_out<<<dim3(Mz / 128, Hz / 128), 256, 0, stream>>>(Ob, Wo_bf, (float*)d_out);
}